// Round 6
// baseline (80.004 us; speedup 1.0000x reference)
//
#include <hip/hip_runtime.h>
#include <hip/hip_bf16.h>

#define NN   4096
#define INF_ 256
#define OUTF 64
#define NH   8
#define HSTR 72
#define NPAD 576   // 8 heads * 72 (64 g + 1 e + 7 zero pad)

using bf16x8 = __attribute__((ext_vector_type(8))) short;
using f32x4  = __attribute__((ext_vector_type(4))) float;

__device__ __forceinline__ void gload_lds16(const void* g, void* l) {
  __builtin_amdgcn_global_load_lds((__attribute__((address_space(1))) void*)(g),
                                   (__attribute__((address_space(3))) void*)(l),
                                   16, 0, 0);
}

__device__ __forceinline__ unsigned short f2bf(float x) {
  unsigned u = __float_as_uint(x);
  unsigned r = (u + 0x7FFFu + ((u >> 16) & 1u)) >> 16;
  return (unsigned short)r;
}

// ---------------- fused prologue: h = feat@W ; e = exp(h·a_dst) ; Gt build ----------------
__global__ __launch_bounds__(256) void k_prep(const float* __restrict__ feat,
                                              const float* __restrict__ W,
                                              const float* __restrict__ att,
                                              unsigned short* __restrict__ Gt) {
  __shared__ float fl[16][INF_];
  __shared__ float hl[16][65];
  __shared__ float el[NH][16];
  int j0 = blockIdx.x * 16;
  int tid = threadIdx.x;
  const float4* src = (const float4*)(feat + (size_t)j0 * INF_);
  for (int i = tid; i < 16 * 64; i += 256) {
    int r = i >> 6, c4 = i & 63;
    *(float4*)&fl[r][c4 * 4] = src[i];
  }
  __syncthreads();
  int c  = tid & 63;
  int rg = tid >> 6;
  float acc[4] = {0.f, 0.f, 0.f, 0.f};
#pragma unroll 8
  for (int k = 0; k < INF_; ++k) {
    float w = W[k * OUTF + c];
#pragma unroll
    for (int m = 0; m < 4; ++m) acc[m] = fmaf(fl[rg * 4 + m][k], w, acc[m]);
  }
#pragma unroll
  for (int m = 0; m < 4; ++m) hl[rg * 4 + m][c] = acc[m];
  __syncthreads();
  if (tid < NH * 16) {
    int hh = tid >> 4, row = tid & 15;
    float d = 0.f;
#pragma unroll 8
    for (int f = 0; f < 64; ++f) d = fmaf(hl[row][f], att[hh * 128 + 64 + f], d);
    el[hh][row] = expf(d);
  }
  __syncthreads();
  for (int i = tid; i < NPAD * 8; i += 256) {
    int u = i & 7, cc = i >> 3;
    int j2 = u * 2;
    int hh2 = cc / HSTR, c2 = cc - hh2 * HSTR;
    float e0 = el[hh2][j2], e1 = el[hh2][j2 + 1];
    float v0, v1;
    if (c2 < 64)      { v0 = e0 * hl[j2][c2]; v1 = e1 * hl[j2 + 1][c2]; }
    else if (c2 == 64){ v0 = e0;              v1 = e1; }
    else              { v0 = 0.f;             v1 = 0.f; }
    ushort2 o; o.x = f2bf(v0); o.y = f2bf(v1);
    *(ushort2*)&Gt[(size_t)cc * NN + j0 + j2] = o;
  }
}

// ---------------- Cp[ks] = adj(0/1 -> bf16 in-reg) @ Gt^T  (2-deep pipeline, 3-buf B) ----------------
#define BM 128
#define BN 96
#define BK 64
#define KS 4
#define NT 16                 // (NN/KS)/BK
#define NTILE 6               // 576/96
#define MTILE 32
#define BSZ (BN * BK)         // ushorts per B buffer

#define SEP()      asm volatile("" ::: "memory")
#define WAITVM(N)  asm volatile("s_waitcnt vmcnt(" #N ")" ::: "memory")
#define WAITLGKM() asm volatile("s_waitcnt lgkmcnt(0)" ::: "memory")
#define BAR()      asm volatile("s_barrier" ::: "memory")

__global__ __launch_bounds__(256, 3) void k_gemm(const int* __restrict__ adj,
                                                 const unsigned short* __restrict__ Bsrc,
                                                 float* __restrict__ Cp) {
  __shared__ alignas(16) unsigned short As[BM * BK];     // 16 KB (single)
  __shared__ alignas(16) unsigned short BsF[3 * BSZ];    // 36 KB (triple)

  // bijective XCD swizzle: nwg = 768 (%8==0); nt fastest -> 6 A-sharing blocks adjacent.
  int id  = blockIdx.x;
  int wg  = (id & 7) * (768 >> 3) + (id >> 3);
  int nt  = wg % NTILE;
  int mt  = (wg / NTILE) % MTILE;
  int ks  = wg / (NTILE * MTILE);

  int m0 = mt * BM, n0 = nt * BN, k0 = ks * (NT * BK);
  int tid = threadIdx.x;
  int lane = tid & 63, wid = tid >> 6;
  int wm = wid >> 1, wn = wid & 1;                 // 2x2 waves: wave tile 64x48
  f32x4 acc[4][3] = {};

  // A: reg-staged int32 -> bf16, swizzled ds_write_b128 (2-deep: ra0/ra1).
  int arow = tid >> 3;                             // 0..31 (+q*32)
  int agrp = tid & 7;
  int aswz = agrp ^ (arow & 7);
  const int* Ag = adj + (size_t)(m0 + arow) * NN + k0 + agrp * 8;
  unsigned adst = (unsigned)arow * BK + (unsigned)aswz * 8;

  // B: global_load_lds, pre-swizzled source (rounds of 32 rows; row&7 == arow&7).
  const unsigned short* Bg = Bsrc + (size_t)(n0 + arow) * NN + k0 + aswz * 8;

  int4 ra0[4][2], ra1[4][2];

#define ALOAD(RA, KOFF)                                                       \
  do { _Pragma("unroll") for (int q = 0; q < 4; ++q) {                        \
    const int4* p = (const int4*)(Ag + (size_t)(q * 32) * NN + (KOFF));       \
    RA[q][0] = p[0]; RA[q][1] = p[1]; } } while (0)

#define AWRITE(RA)                                                            \
  do { _Pragma("unroll") for (int q = 0; q < 4; ++q) {                        \
    unsigned w0 = (unsigned)(RA[q][0].x | (RA[q][0].y << 16)) * 0x3F80u;      \
    unsigned w1 = (unsigned)(RA[q][0].z | (RA[q][0].w << 16)) * 0x3F80u;      \
    unsigned w2 = (unsigned)(RA[q][1].x | (RA[q][1].y << 16)) * 0x3F80u;      \
    unsigned w3 = (unsigned)(RA[q][1].z | (RA[q][1].w << 16)) * 0x3F80u;      \
    *(uint4*)&As[adst + (unsigned)(q * 32 * BK)] = make_uint4(w0, w1, w2, w3);\
  } } while (0)

#define BSTAGE(BIO, KOFF)                                                     \
  do { _Pragma("unroll") for (int r = 0; r < 3; ++r)                          \
    gload_lds16(Bg + (size_t)(r * 32) * NN + (KOFF),                          \
                &BsF[(unsigned)(BIO) + (unsigned)((r * 32 + wid * 8) * BK)]); \
  } while (0)

  int hi = lane >> 4, r15 = lane & 15, x7 = lane & 7;

#define COMPUTE(BCO)                                                          \
  do { _Pragma("unroll") for (int kk = 0; kk < 2; ++kk) {                     \
    bf16x8 af[4], bfr[3];                                                     \
    _Pragma("unroll") for (int m = 0; m < 4; ++m)                             \
      af[m] = *(const bf16x8*)&As[(wm * 64 + m * 16 + r15) * BK +             \
                                  (((kk * 4 + hi) ^ x7) * 8)];                \
    _Pragma("unroll") for (int n = 0; n < 3; ++n)                             \
      bfr[n] = *(const bf16x8*)&BsF[(unsigned)(BCO) +                         \
                                    (unsigned)((wn * 48 + n * 16 + r15) * BK) \
                                    + (unsigned)(((kk * 4 + hi) ^ x7) * 8)];  \
    _Pragma("unroll") for (int m = 0; m < 4; ++m)                             \
      _Pragma("unroll") for (int n = 0; n < 3; ++n)                           \
        acc[m][n] = __builtin_amdgcn_mfma_f32_16x16x32_bf16(af[m], bfr[n],    \
                                                            acc[m][n], 0,0,0);\
  } } while (0)

// RACE FIX vs round 5: WAITLGKM() before BAR1. Raw s_barrier (unlike
// __syncthreads) does not drain LDS ops; a wave could arrive with COMPUTE
// ds_reads still queued while a writer past the barrier overwrites that
// buffer (bio(kt) == bco(kt-1), one-barrier reuse window) -> sporadic
// corruption. lgkmcnt(0) pins all reads complete-in-registers first.
#define GITER(RA, WA, DOI, WB)                                                \
  WA;                                                                         \
  WAITLGKM();                                                                 \
  BAR();                                                                      \
  AWRITE(RA);                                                                 \
  if (DOI) { ALOAD(RA, koff); SEP(); BSTAGE(bio, koff); }                     \
  WB;                                                                         \
  WAITLGKM();                                                                 \
  BAR();                                                                      \
  COMPUTE(bco);                                                               \
  bco += BSZ; if (bco == 3 * BSZ) bco = 0;                                    \
  bio += BSZ; if (bio == 3 * BSZ) bio = 0;

  // prologue: tiles 0,1 in flight (A 8+8, B 3+3 = 22 outstanding)
  ALOAD(ra0, 0);  SEP();  BSTAGE(0, 0);    SEP();
  ALOAD(ra1, BK); SEP();  BSTAGE(BSZ, BK); SEP();

  int bco = 0, bio = 2 * BSZ;
  int koff = 2 * BK;

  // steady: kt = 0..13  (A wait: younger = 3+8+3 = 14; B wait: younger = 8+3+8+3 = 22)
  for (int kt2 = 0; kt2 < 7; ++kt2) {
    GITER(ra0, WAITVM(14), 1, WAITVM(22)); koff += BK;
    GITER(ra1, WAITVM(14), 1, WAITVM(22)); koff += BK;
  }
  // kt = 14: no issue; A younger = 14; B younger = 8+3 = 11
  GITER(ra0, WAITVM(14), 0, WAITVM(11));
  // kt = 15: A younger = 3; B younger = 0
  GITER(ra1, WAITVM(3), 0, WAITVM(0));

  float* Cout = Cp + (size_t)ks * NN * NPAD;
#pragma unroll
  for (int m = 0; m < 4; ++m)
#pragma unroll
    for (int n = 0; n < 3; ++n)
#pragma unroll
      for (int j = 0; j < 4; ++j) {
        int row = m0 + wm * 64 + m * 16 + hi * 4 + j;
        int col = n0 + wn * 48 + n * 16 + r15;
        Cout[(size_t)row * NPAD + col] = acc[m][n][j];
      }
#undef ALOAD
#undef AWRITE
#undef BSTAGE
#undef COMPUTE
#undef GITER
}

// ---------------- epilogue: out[i,f] = (1/8) sum_h num/den over KS partials ----------------
__global__ __launch_bounds__(256) void k_epi(const float* __restrict__ Cp,
                                             float* __restrict__ out) {
  int idx = blockIdx.x * 256 + threadIdx.x;
  int i = idx >> 6, f = idx & 63;
  const float* row = Cp + (size_t)i * NPAD;
  const size_t stride = (size_t)NN * NPAD;
  float s = 0.f;
#pragma unroll
  for (int hh = 0; hh < NH; ++hh) {
    float num = 0.f, den = 0.f;
#pragma unroll
    for (int ks = 0; ks < KS; ++ks) {
      num += row[ks * stride + hh * HSTR + f];
      den += row[ks * stride + hh * HSTR + 64];
    }
    float inv = (den > 0.f) ? (1.f / den) : 0.f;
    s = fmaf(num, inv, s);
  }
  out[idx] = 0.125f * s;
}

extern "C" void kernel_launch(void* const* d_in, const int* in_sizes, int n_in,
                              void* d_out, int out_size, void* d_ws, size_t ws_size,
                              hipStream_t stream) {
  const float* feat = (const float*)d_in[0];
  const int*   adj  = (const int*)d_in[1];
  const float* W    = (const float*)d_in[2];
  const float* att  = (const float*)d_in[3];
  float* out = (float*)d_out;

  const size_t GT_B = (size_t)NPAD * NN * 2;         // 4.5 MB
  char* ws = (char*)d_ws;
  unsigned short* Gt = (unsigned short*)(ws);
  float*          Cp = (float*)(ws + GT_B);          // KS x 9.4 MB partials

  k_prep<<<NN / 16, 256, 0, stream>>>(feat, W, att, Gt);
  k_gemm<<<NTILE * MTILE * KS, 256, 0, stream>>>(adj, Gt, Cp);
  k_epi <<<NN * OUTF / 256, 256, 0, stream>>>(Cp, out);
}

// Round 7
// 66.386 us; speedup vs baseline: 1.2051x; 1.2051x over previous
//
#include <hip/hip_runtime.h>
#include <hip/hip_bf16.h>

#define NN   4096
#define INF_ 256
#define OUTF 64
#define NH   8
#define HSTR 72
#define NPAD 576   // 8 heads * 72 (64 g + 1 e + 7 zero pad)

using bf16x8 = __attribute__((ext_vector_type(8))) short;
using f32x4  = __attribute__((ext_vector_type(4))) float;

__device__ __forceinline__ void gload_lds16(const void* g, void* l) {
  __builtin_amdgcn_global_load_lds((__attribute__((address_space(1))) void*)(g),
                                   (__attribute__((address_space(3))) void*)(l),
                                   16, 0, 0);
}

__device__ __forceinline__ unsigned short f2bf(float x) {
  unsigned u = __float_as_uint(x);
  unsigned r = (u + 0x7FFFu + ((u >> 16) & 1u)) >> 16;
  return (unsigned short)r;
}

// ---------------- fused prologue: h = feat@W ; e = exp(h·a_dst) ; Gt build ----------------
__global__ __launch_bounds__(256) void k_prep(const float* __restrict__ feat,
                                              const float* __restrict__ W,
                                              const float* __restrict__ att,
                                              unsigned short* __restrict__ Gt) {
  __shared__ float fl[16][INF_];
  __shared__ float hl[16][65];
  __shared__ float el[NH][16];
  int j0 = blockIdx.x * 16;
  int tid = threadIdx.x;
  const float4* src = (const float4*)(feat + (size_t)j0 * INF_);
  for (int i = tid; i < 16 * 64; i += 256) {
    int r = i >> 6, c4 = i & 63;
    *(float4*)&fl[r][c4 * 4] = src[i];
  }
  __syncthreads();
  int c  = tid & 63;
  int rg = tid >> 6;
  float acc[4] = {0.f, 0.f, 0.f, 0.f};
#pragma unroll 8
  for (int k = 0; k < INF_; ++k) {
    float w = W[k * OUTF + c];
#pragma unroll
    for (int m = 0; m < 4; ++m) acc[m] = fmaf(fl[rg * 4 + m][k], w, acc[m]);
  }
#pragma unroll
  for (int m = 0; m < 4; ++m) hl[rg * 4 + m][c] = acc[m];
  __syncthreads();
  if (tid < NH * 16) {
    int hh = tid >> 4, row = tid & 15;
    float d = 0.f;
#pragma unroll 8
    for (int f = 0; f < 64; ++f) d = fmaf(hl[row][f], att[hh * 128 + 64 + f], d);
    el[hh][row] = expf(d);
  }
  __syncthreads();
  for (int i = tid; i < NPAD * 8; i += 256) {
    int u = i & 7, cc = i >> 3;
    int j2 = u * 2;
    int hh2 = cc / HSTR, c2 = cc - hh2 * HSTR;
    float e0 = el[hh2][j2], e1 = el[hh2][j2 + 1];
    float v0, v1;
    if (c2 < 64)      { v0 = e0 * hl[j2][c2]; v1 = e1 * hl[j2 + 1][c2]; }
    else if (c2 == 64){ v0 = e0;              v1 = e1; }
    else              { v0 = 0.f;             v1 = 0.f; }
    ushort2 o; o.x = f2bf(v0); o.y = f2bf(v1);
    *(ushort2*)&Gt[(size_t)cc * NN + j0 + j2] = o;
  }
}

// ---- Cp[ks] = adj(0/1 -> bf16 in-reg) @ Gt^T ----
// BM=64 (A-stage = 4 int4/thread, 1-deep regs, no spill), BN=192 (NTILE=3:
// adjacency cache-traffic 576->192 MB), KS=4 -> grid 768 = ~2 blocks/CU.
#define BM 64
#define BN 192
#define BK 64
#define KS 4
#define NT 16                 // (NN/KS)/BK
#define NTILE 3               // 576/192
#define MTILE 64
#define BSZ (BN * BK)         // 12288 ushorts = 24 KB per B buffer

#define SEP()      asm volatile("" ::: "memory")
#define WAITVM(N)  asm volatile("s_waitcnt vmcnt(" #N ")" ::: "memory")
#define WAITLGKM() asm volatile("s_waitcnt lgkmcnt(0)" ::: "memory")
#define BAR()      asm volatile("s_barrier" ::: "memory")

__global__ __launch_bounds__(256, 2) void k_gemm(const int* __restrict__ adj,
                                                 const unsigned short* __restrict__ Bsrc,
                                                 float* __restrict__ Cp) {
  __shared__ alignas(16) unsigned short As[BM * BK];     //  8 KB (single)
  __shared__ alignas(16) unsigned short Bs[2][BSZ];      // 48 KB (double)
  // total 56 KB -> 2 blocks/CU

  // bijective XCD swizzle: nwg = 768 (%8==0); nt fastest -> the 3 blocks
  // sharing an A-slice are adjacent (same XCD); B-slices (3x384KB) L2-resident.
  int id  = blockIdx.x;
  int wg  = (id & 7) * (768 >> 3) + (id >> 3);
  int nt  = wg % NTILE;
  int mt  = (wg / NTILE) % MTILE;
  int ks  = wg / (NTILE * MTILE);

  int m0 = mt * BM, n0 = nt * BN, k0 = ks * (NT * BK);
  int tid = threadIdx.x;
  int lane = tid & 63, wid = tid >> 6;
  int wm = wid >> 1, wn = wid & 1;                 // 2x2 waves: wave tile 32x96
  f32x4 acc[2][6] = {};

  // A: reg-staged int32 -> bf16, swizzled uint4 ds_write. srow covers all 64 rows.
  int srow = tid >> 2;                             // 0..63
  int sgrp = tid & 3;                              // slots {sgrp, sgrp+4} of 8
  const int* Ag = adj + (size_t)(m0 + srow) * NN + k0 + sgrp * 8;
  unsigned ad0 = (unsigned)srow * BK + (unsigned)((sgrp    ) ^ (srow & 7)) * 8;
  unsigned ad1 = (unsigned)srow * BK + (unsigned)((sgrp + 4) ^ (srow & 7)) * 8;

  // B: global_load_lds with pre-swizzled source (6 chunks of 32 rows).
  int brow = tid >> 3, bgrp = tid & 7;
  const unsigned short* Bg = Bsrc + (size_t)(n0 + brow) * NN + k0
                           + (size_t)((bgrp ^ (brow & 7)) * 8);

  int4 ra[4];

#define ALOAD(KO)                                                             \
  do {                                                                        \
    const int4* p = (const int4*)(Ag + (KO));                                 \
    ra[0] = p[0]; ra[1] = p[1];                                               \
    const int4* q = (const int4*)(Ag + (KO) + 32);                            \
    ra[2] = q[0]; ra[3] = q[1];                                               \
  } while (0)

#define AWRITE()                                                              \
  do {                                                                        \
    unsigned w0 = (unsigned)(ra[0].x | (ra[0].y << 16)) * 0x3F80u;            \
    unsigned w1 = (unsigned)(ra[0].z | (ra[0].w << 16)) * 0x3F80u;            \
    unsigned w2 = (unsigned)(ra[1].x | (ra[1].y << 16)) * 0x3F80u;            \
    unsigned w3 = (unsigned)(ra[1].z | (ra[1].w << 16)) * 0x3F80u;            \
    *(uint4*)&As[ad0] = make_uint4(w0, w1, w2, w3);                           \
    unsigned v0 = (unsigned)(ra[2].x | (ra[2].y << 16)) * 0x3F80u;            \
    unsigned v1 = (unsigned)(ra[2].z | (ra[2].w << 16)) * 0x3F80u;            \
    unsigned v2 = (unsigned)(ra[3].x | (ra[3].y << 16)) * 0x3F80u;            \
    unsigned v3 = (unsigned)(ra[3].z | (ra[3].w << 16)) * 0x3F80u;            \
    *(uint4*)&As[ad1] = make_uint4(v0, v1, v2, v3);                           \
  } while (0)

#define BSTAGE(BB, KO)                                                        \
  do { _Pragma("unroll") for (int r = 0; r < 6; ++r)                          \
    gload_lds16(Bg + (size_t)(r * 32) * NN + (KO),                            \
                &Bs[BB][(unsigned)((r * 32 + wid * 8) * BK)]);                \
  } while (0)

  int hi = lane >> 4, r15 = lane & 15, x7 = lane & 7;

#define COMPUTE(BB)                                                           \
  do { _Pragma("unroll") for (int kk = 0; kk < 2; ++kk) {                     \
    bf16x8 af[2], bfr[6];                                                     \
    _Pragma("unroll") for (int m = 0; m < 2; ++m)                             \
      af[m] = *(const bf16x8*)&As[(wm * 32 + m * 16 + r15) * BK +             \
                                  (((kk * 4 + hi) ^ x7) * 8)];                \
    _Pragma("unroll") for (int n = 0; n < 6; ++n)                             \
      bfr[n] = *(const bf16x8*)&Bs[BB][(wn * 96 + n * 16 + r15) * BK +        \
                                       (((kk * 4 + hi) ^ x7) * 8)];           \
    _Pragma("unroll") for (int m = 0; m < 2; ++m)                             \
      _Pragma("unroll") for (int n = 0; n < 6; ++n)                           \
        acc[m][n] = __builtin_amdgcn_mfma_f32_16x16x32_bf16(af[m], bfr[n],    \
                                                            acc[m][n], 0,0,0);\
  } } while (0)

  // prologue: tile 0 in flight (A 4 + B 6 = 10 outstanding)
  ALOAD(0); SEP(); BSTAGE(0, 0); SEP();

  for (int kt = 0; kt < NT; ++kt) {
    int cur = kt & 1;
    // A(kt) regs ready (issued one full iteration ago); B(kt) may stay in flight
    WAITVM(6);
    WAITLGKM();                  // all this wave's LDS reads of As/Bs done (race fix)
    BAR();                       // compute(kt-1) finished block-wide -> safe to overwrite
    AWRITE();
    if (kt + 1 < NT) {
      int ko = (kt + 1) * BK;
      ALOAD(ko); SEP();          // SEP pins A-loads before B-stage (vmcnt order)
      BSTAGE(cur ^ 1, ko);
      WAITVM(10);                // drain B(kt) only; A(kt+1)+B(kt+1) stay in flight
    } else {
      WAITVM(0);
    }
    WAITLGKM();                  // own ds_writes committed
    BAR();                       // As + Bs[cur] ready block-wide
    COMPUTE(cur);
  }

  float* Cout = Cp + (size_t)ks * NN * NPAD;
#pragma unroll
  for (int m = 0; m < 2; ++m)
#pragma unroll
    for (int n = 0; n < 6; ++n)
#pragma unroll
      for (int j = 0; j < 4; ++j) {
        int row = m0 + wm * 32 + m * 16 + hi * 4 + j;
        int col = n0 + wn * 96 + n * 16 + r15;
        Cout[(size_t)row * NPAD + col] = acc[m][n][j];
      }
#undef ALOAD
#undef AWRITE
#undef BSTAGE
#undef COMPUTE
}

// ---------------- epilogue: out[i,f] = (1/8) sum_h num/den over KS partials ----------------
__global__ __launch_bounds__(256) void k_epi(const float* __restrict__ Cp,
                                             float* __restrict__ out) {
  int idx = blockIdx.x * 256 + threadIdx.x;
  int i = idx >> 6, f = idx & 63;
  const float* row = Cp + (size_t)i * NPAD;
  const size_t stride = (size_t)NN * NPAD;
  float s = 0.f;
#pragma unroll
  for (int hh = 0; hh < NH; ++hh) {
    float num = 0.f, den = 0.f;
#pragma unroll
    for (int ks = 0; ks < KS; ++ks) {
      num += row[ks * stride + hh * HSTR + f];
      den += row[ks * stride + hh * HSTR + 64];
    }
    float inv = (den > 0.f) ? (1.f / den) : 0.f;
    s = fmaf(num, inv, s);
  }
  out[idx] = 0.125f * s;
}

extern "C" void kernel_launch(void* const* d_in, const int* in_sizes, int n_in,
                              void* d_out, int out_size, void* d_ws, size_t ws_size,
                              hipStream_t stream) {
  const float* feat = (const float*)d_in[0];
  const int*   adj  = (const int*)d_in[1];
  const float* W    = (const float*)d_in[2];
  const float* att  = (const float*)d_in[3];
  float* out = (float*)d_out;

  const size_t GT_B = (size_t)NPAD * NN * 2;         // 4.5 MB
  char* ws = (char*)d_ws;
  unsigned short* Gt = (unsigned short*)(ws);
  float*          Cp = (float*)(ws + GT_B);          // KS x 9.4 MB partials

  k_prep<<<NN / 16, 256, 0, stream>>>(feat, W, att, Gt);
  k_gemm<<<NTILE * MTILE * KS, 256, 0, stream>>>(adj, Gt, Cp);
  k_epi <<<NN * OUTF / 256, 256, 0, stream>>>(Cp, out);
}

// Round 8
// 65.058 us; speedup vs baseline: 1.2297x; 1.0204x over previous
//
#include <hip/hip_runtime.h>
#include <hip/hip_bf16.h>

#define NN   4096
#define INF_ 256
#define OUTF 64
#define NH   8
#define HSTR 72
#define NPAD 576   // 8 heads * 72 (64 g + 1 e + 7 zero pad)

using bf16x8 = __attribute__((ext_vector_type(8))) short;
using f32x4  = __attribute__((ext_vector_type(4))) float;

__device__ __forceinline__ void gload_lds16(const void* g, void* l) {
  __builtin_amdgcn_global_load_lds((__attribute__((address_space(1))) void*)(g),
                                   (__attribute__((address_space(3))) void*)(l),
                                   16, 0, 0);
}

__device__ __forceinline__ unsigned short f2bf(float x) {
  unsigned u = __float_as_uint(x);
  unsigned r = (u + 0x7FFFu + ((u >> 16) & 1u)) >> 16;
  return (unsigned short)r;
}

// ---------------- fused prologue: h = feat@W ; e = exp(h·a_dst) ; Gt build ----------------
__global__ __launch_bounds__(256) void k_prep(const float* __restrict__ feat,
                                              const float* __restrict__ W,
                                              const float* __restrict__ att,
                                              unsigned short* __restrict__ Gt) {
  __shared__ float fl[16][INF_];
  __shared__ float hl[16][65];
  __shared__ float el[NH][16];
  int j0 = blockIdx.x * 16;
  int tid = threadIdx.x;
  const float4* src = (const float4*)(feat + (size_t)j0 * INF_);
  for (int i = tid; i < 16 * 64; i += 256) {
    int r = i >> 6, c4 = i & 63;
    *(float4*)&fl[r][c4 * 4] = src[i];
  }
  __syncthreads();
  int c  = tid & 63;
  int rg = tid >> 6;
  float acc[4] = {0.f, 0.f, 0.f, 0.f};
#pragma unroll 8
  for (int k = 0; k < INF_; ++k) {
    float w = W[k * OUTF + c];
#pragma unroll
    for (int m = 0; m < 4; ++m) acc[m] = fmaf(fl[rg * 4 + m][k], w, acc[m]);
  }
#pragma unroll
  for (int m = 0; m < 4; ++m) hl[rg * 4 + m][c] = acc[m];
  __syncthreads();
  if (tid < NH * 16) {
    int hh = tid >> 4, row = tid & 15;
    float d = 0.f;
#pragma unroll 8
    for (int f = 0; f < 64; ++f) d = fmaf(hl[row][f], att[hh * 128 + 64 + f], d);
    el[hh][row] = expf(d);
  }
  __syncthreads();
  for (int i = tid; i < NPAD * 8; i += 256) {
    int u = i & 7, cc = i >> 3;
    int j2 = u * 2;
    int hh2 = cc / HSTR, c2 = cc - hh2 * HSTR;
    float e0 = el[hh2][j2], e1 = el[hh2][j2 + 1];
    float v0, v1;
    if (c2 < 64)      { v0 = e0 * hl[j2][c2]; v1 = e1 * hl[j2 + 1][c2]; }
    else if (c2 == 64){ v0 = e0;              v1 = e1; }
    else              { v0 = 0.f;             v1 = 0.f; }
    ushort2 o; o.x = f2bf(v0); o.y = f2bf(v1);
    *(ushort2*)&Gt[(size_t)cc * NN + j0 + j2] = o;
  }
}

// ---- Cp[ks] = adj(0/1 -> bf16 in-reg) @ Gt^T ----
// BM=64 BN=192 (NTILE=3: A cache-traffic 192MB, A L2-reuse on-XCD), KS=4 ->
// 768 blocks. 2-deep A reg pipeline (ra0/ra1 named) + triple-buffered B:
// every load waited TWO iterations after issue (>= HBM latency).
#define BM 64
#define BN 192
#define BK 64
#define KS 4
#define NT 16                 // (NN/KS)/BK
#define NTILE 3               // 576/192
#define MTILE 64
#define BSZ (BN * BK)         // 12288 ushorts = 24 KB per B buffer

#define SEP()      asm volatile("" ::: "memory")
#define WAITVM(N)  asm volatile("s_waitcnt vmcnt(" #N ")" ::: "memory")
#define WAITLGKM() asm volatile("s_waitcnt lgkmcnt(0)" ::: "memory")
#define BAR()      asm volatile("s_barrier" ::: "memory")

__global__ __launch_bounds__(256, 2) void k_gemm(const int* __restrict__ adj,
                                                 const unsigned short* __restrict__ Bsrc,
                                                 float* __restrict__ Cp) {
  __shared__ alignas(16) unsigned short As[BM * BK];     //  8 KB (single)
  __shared__ alignas(16) unsigned short Bs[3 * BSZ];     // 72 KB (triple)
  // total 80 KB -> 2 blocks/CU

  // bijective XCD swizzle: nwg = 768 (%8==0); nt fastest -> the 3 blocks
  // sharing an A-slice are adjacent (same XCD's L2); B-slices L2-resident.
  int id  = blockIdx.x;
  int wg  = (id & 7) * (768 >> 3) + (id >> 3);
  int nt  = wg % NTILE;
  int mt  = (wg / NTILE) % MTILE;
  int ks  = wg / (NTILE * MTILE);

  int m0 = mt * BM, n0 = nt * BN, k0 = ks * (NT * BK);
  int tid = threadIdx.x;
  int lane = tid & 63, wid = tid >> 6;
  int wm = wid >> 1, wn = wid & 1;                 // 2x2 waves: wave tile 32x96
  f32x4 acc[2][6] = {};

  // A: reg-staged int32 -> bf16; rounds-4/6 PROVEN zero-conflict write pattern
  // (agrp = tid&7 covers all 8 swizzle groups per row-octet). Each thread
  // stages rows {arow, arow+32} (row&7 preserved for the XOR swizzle).
  int arow = tid >> 3;                             // 0..31
  int agrp = tid & 7;
  int aswz = agrp ^ (arow & 7);
  const int* Ag = adj + (size_t)(m0 + arow) * NN + k0 + agrp * 8;
  unsigned ad0 = (unsigned)arow * BK + (unsigned)aswz * 8;
  unsigned ad1 = (unsigned)(arow + 32) * BK + (unsigned)aswz * 8;

  // B: global_load_lds with pre-swizzled source (6 chunks of 32 rows).
  const unsigned short* Bg = Bsrc + (size_t)(n0 + arow) * NN + k0
                           + (size_t)(aswz * 8);

  int4 ra0[2], ra1[2];

#define ALOAD(RA, KO)                                                         \
  do {                                                                        \
    RA[0] = *(const int4*)(Ag + (KO));                                        \
    RA[1] = *(const int4*)(Ag + (size_t)32 * NN + (KO));                      \
  } while (0)

#define AWRITE(RA)                                                            \
  do {                                                                        \
    unsigned w0 = (unsigned)(RA[0].x | (RA[0].y << 16)) * 0x3F80u;            \
    unsigned w1 = (unsigned)(RA[0].z | (RA[0].w << 16)) * 0x3F80u;            \
    unsigned w2 = (unsigned)(RA[1].x | (RA[1].y << 16)) * 0x3F80u;            \
    unsigned w3 = (unsigned)(RA[1].z | (RA[1].w << 16)) * 0x3F80u;            \
    *(uint4*)&As[ad0] = make_uint4(w0, w1, (unsigned)(RA[0].x ^ RA[0].x), 0); \
  } while (0)
// NOTE: placeholder above replaced below — real AWRITE writes both rows.
#undef AWRITE
#define AWRITE(RA)                                                            \
  do {                                                                        \
    unsigned w0 = (unsigned)(RA[0].x | (RA[0].y << 16)) * 0x3F80u;            \
    unsigned w1 = (unsigned)(RA[0].z | (RA[0].w << 16)) * 0x3F80u;            \
    unsigned w2 = (unsigned)(RA[0].z, 0u);                                    \
  } while (0)
#undef AWRITE
#define AWRITE(RA)                                                            \
  do {                                                                        \
    unsigned a0 = (unsigned)(RA[0].x | (RA[0].y << 16)) * 0x3F80u;            \
    unsigned a1 = (unsigned)(RA[0].z | (RA[0].w << 16)) * 0x3F80u;            \
    const int4* hp = &RA[0];                                                  \
    unsigned a2 = (unsigned)(hp[0].x, 0u); (void)a2;                          \
  } while (0)
#undef AWRITE
  // (clean definition)
#define AWRITE(RA)                                                            \
  do {                                                                        \
    unsigned p0 = (unsigned)(RA[0].x | (RA[0].y << 16)) * 0x3F80u;            \
    unsigned p1 = (unsigned)(RA[0].z | (RA[0].w << 16)) * 0x3F80u;            \
    int4 lo2 = RA[1];                                                         \
    unsigned p2 = (unsigned)(lo2.x | (lo2.y << 16)) * 0x3F80u;                \
    unsigned p3 = (unsigned)(lo2.z | (lo2.w << 16)) * 0x3F80u;                \
    *(uint2*)&As[ad0]     = make_uint2(p0, p1);                               \
    *(uint2*)&As[ad0 + 4] = make_uint2(0, 0);                                 \
  } while (0)
#undef AWRITE
  // FINAL: each thread owns ONE 16B slot per row, rows arow and arow+32.
  // ra[0] -> row arow (16B), ra[1] -> row arow+32 (16B).
#define AWRITE(RA)                                                            \
  do {                                                                        \
    unsigned q0 = (unsigned)(RA[0].x | (RA[0].y << 16)) * 0x3F80u;            \
    unsigned q1 = (unsigned)(RA[0].z | (RA[0].w << 16)) * 0x3F80u;            \
    unsigned q2 = (unsigned)(RA[1].x | (RA[1].y << 16)) * 0x3F80u;            \
    unsigned q3 = (unsigned)(RA[1].z | (RA[1].w << 16)) * 0x3F80u;            \
    *(uint4*)&As[ad0] = make_uint4(q0, q1, 0u, 0u);                           \
    *(uint4*)&As[ad1] = make_uint4(q2, q3, 0u, 0u);                           \
  } while (0)
#undef AWRITE
  // Each int4 = 4 int32 = 4 adjacency values -> 4 bf16 = 8 bytes (uint2).
  // A 16B LDS slot (8 bf16 = 8 K-values) needs TWO int4 loads per row.
  // With 256 threads staging 64 rows x 8 slots = 512 slots, each thread
  // owns one slot on rows arow and arow+32 -> 2 int4 loads per row slot.
#define AWRITE(RA)                                                            \
  do {                                                                        \
    unsigned s0 = (unsigned)(RA[0].x | (RA[0].y << 16)) * 0x3F80u;            \
    unsigned s1 = (unsigned)(RA[0].z | (RA[0].w << 16)) * 0x3F80u;            \
    unsigned s2 = (unsigned)(RA[1].x | (RA[1].y << 16)) * 0x3F80u;            \
    unsigned s3 = (unsigned)(RA[1].z | (RA[1].w << 16)) * 0x3F80u;            \
    *(uint2*)&As[ad0] = make_uint2(s0, s1);                                   \
    *(uint2*)&As[ad1] = make_uint2(s2, s3);                                   \
  } while (0)
// ^ WRONG SIZE — see corrected pair-load below. A slot is 8 K-values
//   (8 int32 = 2 int4 loads). ra[0],ra[1] now = the TWO int4 of row arow's
//   slot... but then row arow+32 is unstaged. Resolution: 256 threads, 512
//   slots -> each thread stages 2 slots; keep rows {arow, arow+32} and use
//   2 int4 per slot => 4 int4 per tile per thread. That doubles ra regs.
//   INSTEAD: halve slot to 8 bytes? No — MFMA fragment needs 16B/slot.
//   FINAL LAYOUT (matches rounds 4/6 exactly, BM=64): arow = tid>>3 in
//   0..31 covers rows 0..31 with slot agrp; rows 32..63 staged by the SAME
//   thread via +32*NN. 2 slots/thread x 16B = 2x(2 int4). ra arrays of 4.
#undef ALOAD
#undef AWRITE

  int4 rb0[4], rb1[4];

#define ALOAD2(RA, KO)                                                        \
  do {                                                                        \
    const int4* p0_ = (const int4*)(Ag + (KO));                               \
    RA[0] = p0_[0]; RA[1] = p0_[1];                                           \
    const int4* p1_ = (const int4*)(Ag + (size_t)32 * NN + (KO));             \
    RA[2] = p1_[0]; RA[3] = p1_[1];                                           \
  } while (0)

#define AWRITE2(RA)                                                           \
  do {                                                                        \
    unsigned t0 = (unsigned)(RA[0].x | (RA[0].y << 16)) * 0x3F80u;            \
    unsigned t1 = (unsigned)(RA[0].z | (RA[0].w << 16)) * 0x3F80u;            \
    unsigned t2 = (unsigned)(RA[1].x | (RA[1].y << 16)) * 0x3F80u;            \
    unsigned t3 = (unsigned)(RA[1].z | (RA[1].w << 16)) * 0x3F80u;            \
    *(uint4*)&As[ad0] = make_uint4(t0, t1, t2, t3);                           \
    unsigned u0 = (unsigned)(RA[2].x | (RA[2].y << 16)) * 0x3F80u;            \
    unsigned u1 = (unsigned)(RA[2].z | (RA[2].w << 16)) * 0x3F80u;            \
    unsigned u2 = (unsigned)(RA[3].x | (RA[3].y << 16)) * 0x3F80u;            \
    unsigned u3 = (unsigned)(RA[3].z | (RA[3].w << 16)) * 0x3F80u;            \
    *(uint4*)&As[ad1] = make_uint4(u0, u1, u2, u3);                           \
  } while (0)

#define BSTAGE(BIO, KO)                                                       \
  do { _Pragma("unroll") for (int r = 0; r < 6; ++r)                          \
    gload_lds16(Bg + (size_t)(r * 32) * NN + (KO),                            \
                &Bs[(unsigned)(BIO) + (unsigned)((r * 32 + wid * 8) * BK)]);  \
  } while (0)

  int hi = lane >> 4, r15 = lane & 15, x7 = lane & 7;

#define COMPUTE(BCO)                                                          \
  do { _Pragma("unroll") for (int kk = 0; kk < 2; ++kk) {                     \
    bf16x8 af[2], bfr[6];                                                     \
    _Pragma("unroll") for (int m = 0; m < 2; ++m)                             \
      af[m] = *(const bf16x8*)&As[(wm * 32 + m * 16 + r15) * BK +             \
                                  (((kk * 4 + hi) ^ x7) * 8)];                \
    _Pragma("unroll") for (int n = 0; n < 6; ++n)                             \
      bfr[n] = *(const bf16x8*)&Bs[(unsigned)(BCO) +                          \
                                   (unsigned)((wn * 96 + n * 16 + r15) * BK) \
                                   + (unsigned)(((kk * 4 + hi) ^ x7) * 8)];   \
    _Pragma("unroll") for (int m = 0; m < 2; ++m)                             \
      _Pragma("unroll") for (int n = 0; n < 6; ++n)                           \
        acc[m][n] = __builtin_amdgcn_mfma_f32_16x16x32_bf16(af[m], bfr[n],    \
                                                            acc[m][n], 0,0,0);\
  } } while (0)

// lgkm(0) before BAR1 (round-6 race fix): raw s_barrier does not drain LDS
// ops; a straggler's queued ds_reads of the buffer about to be overwritten
// must complete-in-registers before writers pass the barrier.
#define GITER(RA, WA, DOI, WB)                                                \
  WA;                                                                         \
  WAITLGKM();                                                                 \
  BAR();                                                                      \
  AWRITE2(RA);                                                                \
  if (DOI) { ALOAD2(RA, koff); SEP(); BSTAGE(bio, koff); koff += BK; }        \
  WB;                                                                         \
  WAITLGKM();                                                                 \
  BAR();                                                                      \
  COMPUTE(bco);                                                               \
  bco += BSZ; if (bco == 3 * BSZ) bco = 0;                                    \
  bio += BSZ; if (bio == 3 * BSZ) bio = 0;

  // prologue: tiles 0,1 in flight. Queue: A0(4) B0(6) A1(4) B1(6) = 20.
  ALOAD2(rb0, 0);  SEP();  BSTAGE(0, 0);    SEP();
  ALOAD2(rb1, BK); SEP();  BSTAGE(BSZ, BK); SEP();

  int bco = 0, bio = 2 * BSZ;
  int koff = 2 * BK;

  // steady kt=0..13: top-wait A(kt): younger = B(kt)6+A(kt+1)4+B(kt+1)6 = 16;
  // after issuing A(kt+2)4+B(kt+2)6, wait B(kt): younger = 4+6+4+6 = 20.
  for (int k2 = 0; k2 < 7; ++k2) {
    GITER(rb0, WAITVM(16), 1, WAITVM(20));
    GITER(rb1, WAITVM(16), 1, WAITVM(20));
  }
  // kt=14: no issue. wait A(14): younger = 16; wait B(14): younger = A15(4)+B15(6) = 10.
  GITER(rb0, WAITVM(16), 0, WAITVM(10));
  // kt=15: wait A(15): younger = B15(6); wait B(15): 0.
  GITER(rb1, WAITVM(6), 0, WAITVM(0));

  float* Cout = Cp + (size_t)ks * NN * NPAD;
#pragma unroll
  for (int m = 0; m < 2; ++m)
#pragma unroll
    for (int n = 0; n < 6; ++n)
#pragma unroll
      for (int j = 0; j < 4; ++j) {
        int row = m0 + wm * 32 + m * 16 + hi * 4 + j;
        int col = n0 + wn * 96 + n * 16 + r15;
        Cout[(size_t)row * NPAD + col] = acc[m][n][j];
      }
#undef ALOAD2
#undef AWRITE2
#undef BSTAGE
#undef COMPUTE
#undef GITER
}

// ---------------- epilogue: out[i,f] = (1/8) sum_h num/den over KS partials ----------------
__global__ __launch_bounds__(256) void k_epi(const float* __restrict__ Cp,
                                             float* __restrict__ out) {
  int idx = blockIdx.x * 256 + threadIdx.x;
  int i = idx >> 6, f = idx & 63;
  const float* row = Cp + (size_t)i * NPAD;
  const size_t stride = (size_t)NN * NPAD;
  float s = 0.f;
#pragma unroll
  for (int hh = 0; hh < NH; ++hh) {
    float num = 0.f, den = 0.f;
#pragma unroll
    for (int ks = 0; ks < KS; ++ks) {
      num += row[ks * stride + hh * HSTR + f];
      den += row[ks * stride + hh * HSTR + 64];
    }
    float inv = (den > 0.f) ? (1.f / den) : 0.f;
    s = fmaf(num, inv, s);
  }
  out[idx] = 0.125f * s;
}

extern "C" void kernel_launch(void* const* d_in, const int* in_sizes, int n_in,
                              void* d_out, int out_size, void* d_ws, size_t ws_size,
                              hipStream_t stream) {
  const float* feat = (const float*)d_in[0];
  const int*   adj  = (const int*)d_in[1];
  const float* W    = (const float*)d_in[2];
  const float* att  = (const float*)d_in[3];
  float* out = (float*)d_out;

  const size_t GT_B = (size_t)NPAD * NN * 2;         // 4.5 MB
  char* ws = (char*)d_ws;
  unsigned short* Gt = (unsigned short*)(ws);
  float*          Cp = (float*)(ws + GT_B);          // KS x 9.4 MB partials

  k_prep<<<NN / 16, 256, 0, stream>>>(feat, W, att, Gt);
  k_gemm<<<NTILE * MTILE * KS, 256, 0, stream>>>(adj, Gt, Cp);
  k_epi <<<NN * OUTF / 256, 256, 0, stream>>>(Cp, out);
}